// Round 5
// baseline (1825.126 us; speedup 1.0000x reference)
//
#include <hip/hip_runtime.h>
#include <cstdint>

typedef __bf16 bf16_t;
typedef __bf16 bf16x8 __attribute__((ext_vector_type(8)));
typedef __bf16 bf16x4 __attribute__((ext_vector_type(4)));
typedef float f32x4 __attribute__((ext_vector_type(4)));

#define NTOK 4096
#define DIM 768
#define DEPTH 6
#define HEADS 12
#define FFD 3072
#define VOUT 102

__device__ __forceinline__ void gl_lds16(const void* g, void* l) {
    __builtin_amdgcn_global_load_lds(
        (__attribute__((address_space(1))) void*)(g),
        (__attribute__((address_space(3))) void*)(l), 16, 0, 0);
}

__device__ __forceinline__ unsigned enc_f32(float f) {
    unsigned u = __float_as_uint(f);
    return (u & 0x80000000u) ? ~u : (u | 0x80000000u);
}
__device__ __forceinline__ float dec_f32(unsigned e) {
    unsigned u = (e & 0x80000000u) ? (e & 0x7FFFFFFFu) : ~e;
    return __uint_as_float(u);
}

// ---------------- MFMA GEMM: C[M,N] = A[M,K] @ B^T[N,K] ----------------
// MODE 2:  bf16 out = gelu(dot + bias[col])
// MODE 4:  atomicAdd f32 out += dot + (chunk==0 ? bias[col]:0), col<Nvalid  (logits)
// MODE 8:  fused QKV epilogue (QKbf*dn + diag; V -> VT transpose; kmx init)
// MODE 9:  f32 plain store to Cout + bz*sC, row < Mvalid     (ctx chunks)
// MODE 10: bf16 plain store to Cout + bz*sC                  (Wo/FF2 partials)
template<int MODE>
__global__ __launch_bounds__(256, 2) void gemm128(
    const bf16_t* __restrict__ A, int lda, long sA,
    const bf16_t* __restrict__ B, int ldb, long sB,
    void* __restrict__ Cout, int ldc, long sC,
    int K, int nsplit,
    const float* __restrict__ bias,
    const float* __restrict__ rowscale,
    int Mvalid, int Nvalid, void* __restrict__ aux)
{
    __shared__ __align__(16) bf16_t smem[16896];
    bf16_t* As = smem;
    bf16_t* Bs = smem + 8192;
    const int bz = blockIdx.z;
    const int batch = bz / nsplit, chunk = bz % nsplit;
    A += (long)batch * sA;
    B += (long)batch * sB;
    const int t = threadIdx.x;
    const int wave = t >> 6, lane = t & 63;
    const int wm = wave >> 1, wn = wave & 1;
    const int q = lane >> 4, r = lane & 15;
    const int tileM = blockIdx.x * 128, tileN = blockIdx.y * 128;
    const int Kc = K / nsplit;
    const int k0 = chunk * Kc;

    f32x4 acc[4][4] = {};

    for (int kt = 0; kt < Kc; kt += 64) {
        const int kb = k0 + kt;
#pragma unroll
        for (int i = 0; i < 4; i++) {
            const int c = i * 256 + t;
            const int row = c >> 3, kk = (c & 7) * 8;
            gl_lds16(A + (long)(tileM + row) * lda + kb + kk, (char*)As + (i * 256 + wave * 64) * 16);
            gl_lds16(B + (long)(tileN + row) * ldb + kb + kk, (char*)Bs + (i * 256 + wave * 64) * 16);
        }
        __syncthreads();
#pragma unroll
        for (int kk = 0; kk < 64; kk += 32) {
            bf16x8 af[4], bfr[4];
#pragma unroll
            for (int i = 0; i < 4; i++)
                af[i] = *(const bf16x8*)(As + (wm * 64 + i * 16 + r) * 64 + kk + q * 8);
#pragma unroll
            for (int j = 0; j < 4; j++)
                bfr[j] = *(const bf16x8*)(Bs + (wn * 64 + j * 16 + r) * 64 + kk + q * 8);
#pragma unroll
            for (int i = 0; i < 4; i++)
#pragma unroll
                for (int j = 0; j < 4; j++)
                    acc[i][j] = __builtin_amdgcn_mfma_f32_16x16x32_bf16(af[i], bfr[j], acc[i][j], 0, 0, 0);
        }
        __syncthreads();
    }

    if (MODE == 8) {
        // kmx lives immediately after VT (alloc order guarantees it); init to -inf for
        // the downstream qk_feat atomicMax. Stream order makes this race-free.
        if (blockIdx.x == 0 && blockIdx.y == 0 && t < 12) {
            unsigned* kmx = (unsigned*)((bf16_t*)aux + (long)12 * 128 * 4096);
            kmx[t] = enc_f32(-3.0e38f);
        }
        const float dn = 0.3535533905932738f;  // 64^-0.25
        if (tileN < 1536) {
            bf16_t* QK = (bf16_t*)Cout;                 // [4096][1536]
            const int hcol = (tileN >> 6) + wn;         // 0..23
            float* dptr = (hcol < 12) ? ((float*)bias + (long)hcol * 4096)
                                      : ((float*)rowscale + (long)(hcol - 12) * 4096);
#pragma unroll
            for (int i = 0; i < 4; i++) {
#pragma unroll
                for (int e = 0; e < 4; e++) {
                    const int R = tileM + wm * 64 + i * 16 + q * 4 + e;
                    float ss = 0.0f;
#pragma unroll
                    for (int j = 0; j < 4; j++) {
                        const int Cc = tileN + wn * 64 + j * 16 + r;
                        const float v = acc[i][j][e] * dn;
                        QK[(long)R * 1536 + Cc] = (bf16_t)v;
                        ss += v * v;
                    }
                    for (int o = 8; o; o >>= 1) ss += __shfl_xor(ss, o);
                    if (r == 0) dptr[R] = 0.5f * ss;
                }
            }
        } else {
            bf16_t* VTp = (bf16_t*)aux;                 // [12][128][4096]
            bf16_t* tile = smem;                        // [128 cols][130]
#pragma unroll
            for (int i = 0; i < 4; i++)
#pragma unroll
                for (int j = 0; j < 4; j++)
#pragma unroll
                    for (int e = 0; e < 4; e++) {
                        const int row = wm * 64 + i * 16 + q * 4 + e;
                        const int col = wn * 64 + j * 16 + r;
                        tile[col * 130 + row] = (bf16_t)acc[i][j][e];
                    }
            __syncthreads();
            const int col = t >> 1, half = (t & 1) * 64;
            const int cg = tileN - 1536 + col;
            const int h = cg >> 6, d = cg & 63;
            bf16_t* dst = VTp + ((long)h * 128 + d) * 4096 + tileM + half;
            const bf16_t* src = tile + col * 130 + half;
#pragma unroll
            for (int u2 = 0; u2 < 64; u2 += 8)
                *(bf16x8*)(dst + u2) = *(const bf16x8*)(src + u2);
        }
        return;
    }

#pragma unroll
    for (int i = 0; i < 4; i++) {
#pragma unroll
        for (int j = 0; j < 4; j++) {
#pragma unroll
            for (int e = 0; e < 4; e++) {
                const int R = tileM + wm * 64 + i * 16 + q * 4 + e;
                const int Cc = tileN + wn * 64 + j * 16 + r;
                const float v = acc[i][j][e];
                if (MODE == 2) {
                    const float x = v + bias[Cc];
                    const float z = 0.7978845608028654f * (x + 0.044715f * x * x * x);
                    const float th = 1.0f - 2.0f / (__expf(2.0f * z) + 1.0f);
                    bf16_t* Gp = (bf16_t*)Cout;
                    Gp[(long)R * ldc + Cc] = (bf16_t)(0.5f * x * (1.0f + th));
                } else if (MODE == 4) {
                    if (Cc < Nvalid) {
                        float* C = (float*)Cout;
                        atomicAdd(&C[(long)R * ldc + Cc], v + (chunk == 0 ? bias[Cc] : 0.0f));
                    }
                } else if (MODE == 9) {
                    if (R < Mvalid) {
                        float* C = (float*)Cout + (long)bz * sC;
                        C[(long)R * ldc + Cc] = v;
                    }
                } else if (MODE == 10) {
                    bf16_t* C = (bf16_t*)Cout + (long)bz * sC;
                    C[(long)R * ldc + Cc] = (bf16_t)v;
                }
            }
        }
    }
}

// ---------------- combined q-features + k-global-max (grid y: 0..11 q, 12..23 k) -----
__global__ __launch_bounds__(256, 2) void qk_feat(
    const bf16_t* __restrict__ QKbf,      // [4096][1536]
    const bf16_t* __restrict__ projbf,    // [256][64]
    const float* __restrict__ diagQ,      // [12][4096]
    bf16_t* __restrict__ QF,              // [12][4096][256]
    unsigned* __restrict__ kmx)           // [12] encoded
{
    __shared__ __align__(16) bf16_t As[128 * 64];
    __shared__ __align__(16) bf16_t Bs[256 * 64];
    __shared__ float rmax[2][128];
    const int z = blockIdx.y;
    const bool isq = z < 12;
    const int h = isq ? z : z - 12;
    const int tileM = blockIdx.x * 128;
    const int t = threadIdx.x, wave = t >> 6, lane = t & 63;
    const int wm = wave >> 1, wn = wave & 1;
    const int q = lane >> 4, r = lane & 15;
    const bf16_t* A = QKbf + (isq ? 0 : 768) + h * 64;

#pragma unroll
    for (int i = 0; i < 4; i++) {
        const int c = i * 256 + t;
        gl_lds16(A + (long)(tileM + (c >> 3)) * 1536 + (c & 7) * 8, (char*)As + (i * 256 + wave * 64) * 16);
    }
#pragma unroll
    for (int i = 0; i < 8; i++) {
        const int c = i * 256 + t;
        gl_lds16(projbf + c * 8, (char*)Bs + (i * 256 + wave * 64) * 16);
    }
    __syncthreads();

    f32x4 acc[4][8] = {};
#pragma unroll
    for (int kk = 0; kk < 64; kk += 32) {
        bf16x8 af[4], bfr[8];
#pragma unroll
        for (int i = 0; i < 4; i++)
            af[i] = *(const bf16x8*)(As + (wm * 64 + i * 16 + r) * 64 + kk + q * 8);
#pragma unroll
        for (int j = 0; j < 8; j++)
            bfr[j] = *(const bf16x8*)(Bs + (wn * 128 + j * 16 + r) * 64 + kk + q * 8);
#pragma unroll
        for (int i = 0; i < 4; i++)
#pragma unroll
            for (int j = 0; j < 8; j++)
                acc[i][j] = __builtin_amdgcn_mfma_f32_16x16x32_bf16(af[i], bfr[j], acc[i][j], 0, 0, 0);
    }

    if (!isq) {
        float m = -3.0e38f;
#pragma unroll
        for (int i = 0; i < 4; i++)
#pragma unroll
            for (int j = 0; j < 8; j++)
#pragma unroll
                for (int e = 0; e < 4; e++) m = fmaxf(m, acc[i][j][e]);
        for (int o = 32; o; o >>= 1) m = fmaxf(m, __shfl_xor(m, o));
        if (lane == 0) rmax[0][wave] = m;
        __syncthreads();
        if (t == 0) {
            m = fmaxf(fmaxf(rmax[0][0], rmax[0][1]), fmaxf(rmax[0][2], rmax[0][3]));
            atomicMax(kmx + h, enc_f32(m));
        }
        return;
    }

#pragma unroll
    for (int i = 0; i < 4; i++) {
#pragma unroll
        for (int e = 0; e < 4; e++) {
            float m = acc[i][0][e];
#pragma unroll
            for (int j = 1; j < 8; j++) m = fmaxf(m, acc[i][j][e]);
            for (int o = 8; o; o >>= 1) m = fmaxf(m, __shfl_xor(m, o));
            if (r == 0) rmax[wn][wm * 64 + i * 16 + q * 4 + e] = m;
        }
    }
    __syncthreads();
    const float ratio = 0.0625f;
#pragma unroll
    for (int i = 0; i < 4; i++) {
#pragma unroll
        for (int e = 0; e < 4; e++) {
            const int rl = wm * 64 + i * 16 + q * 4 + e;
            const int R = tileM + rl;
            const float dg = diagQ[h * 4096 + R] + fmaxf(rmax[0][rl], rmax[1][rl]);
            bf16_t* op = QF + ((long)h * 4096 + R) * 256 + wn * 128 + r;
#pragma unroll
            for (int j = 0; j < 8; j++)
                op[j * 16] = (bf16_t)(ratio * (__expf(acc[i][j][e] - dg) + 1e-4f));
        }
    }
}

// ---------------- k-features: recompute xd, exp, LDS-transpose -> KFT[h][m][n] -------
__global__ __launch_bounds__(256, 2) void kfeat_fused(
    const bf16_t* __restrict__ QKbf,
    const bf16_t* __restrict__ projbf,
    const float* __restrict__ diagK,
    const unsigned* __restrict__ kmxe,
    const float* __restrict__ maskf,
    bf16_t* __restrict__ KFT)             // [12][256][4096]
{
    __shared__ __align__(16) bf16_t smem[24576];
    bf16_t* As = smem;
    bf16_t* Bs = smem + 8192;
    const int h = blockIdx.y;
    const int tileM = blockIdx.x * 128;
    const int t = threadIdx.x, wave = t >> 6, lane = t & 63;
    const int wm = wave >> 1, wn = wave & 1;
    const int q = lane >> 4, r = lane & 15;
    const bf16_t* A = QKbf + 768 + h * 64;

#pragma unroll
    for (int i = 0; i < 4; i++) {
        const int c = i * 256 + t;
        gl_lds16(A + (long)(tileM + (c >> 3)) * 1536 + (c & 7) * 8, (char*)As + (i * 256 + wave * 64) * 16);
    }
#pragma unroll
    for (int i = 0; i < 8; i++) {
        const int c = i * 256 + t;
        gl_lds16(projbf + c * 8, (char*)Bs + (i * 256 + wave * 64) * 16);
    }
    __syncthreads();

    f32x4 acc[4][8] = {};
#pragma unroll
    for (int kk = 0; kk < 64; kk += 32) {
        bf16x8 af[4], bfr[8];
#pragma unroll
        for (int i = 0; i < 4; i++)
            af[i] = *(const bf16x8*)(As + (wm * 64 + i * 16 + r) * 64 + kk + q * 8);
#pragma unroll
        for (int j = 0; j < 8; j++)
            bfr[j] = *(const bf16x8*)(Bs + (wn * 128 + j * 16 + r) * 64 + kk + q * 8);
#pragma unroll
        for (int i = 0; i < 4; i++)
#pragma unroll
            for (int j = 0; j < 8; j++)
                acc[i][j] = __builtin_amdgcn_mfma_f32_16x16x32_bf16(af[i], bfr[j], acc[i][j], 0, 0, 0);
    }

    const float km = dec_f32(kmxe[h]);
    const float ratio = 0.0625f;
    float dg[4][4], mk[4][4];
#pragma unroll
    for (int i = 0; i < 4; i++)
#pragma unroll
        for (int e = 0; e < 4; e++) {
            const int R = tileM + wm * 64 + i * 16 + q * 4 + e;
            dg[i][e] = diagK[h * 4096 + R] + km;
            mk[i][e] = maskf[R];
        }

    bf16_t* tile = smem;   // [128 m][136]
#pragma unroll
    for (int mhalf = 0; mhalf < 2; mhalf++) {
        __syncthreads();
        if (wn == mhalf) {
#pragma unroll
            for (int i = 0; i < 4; i++)
#pragma unroll
                for (int j = 0; j < 8; j++)
#pragma unroll
                    for (int e = 0; e < 4; e++) {
                        const int rl = wm * 64 + i * 16 + q * 4 + e;
                        const int lc = j * 16 + r;
                        tile[lc * 136 + rl] =
                            (bf16_t)(ratio * (__expf(acc[i][j][e] - dg[i][e]) + 1e-4f) * mk[i][e]);
                    }
        }
        __syncthreads();
        const int m = t >> 1, nb = (t & 1) * 64;
        bf16_t* dst = KFT + ((long)h * 256 + mhalf * 128 + m) * 4096 + tileM + nb;
        const bf16_t* src = tile + m * 136 + nb;
#pragma unroll
        for (int c = 0; c < 64; c += 8)
            *(bf16x8*)(dst + c) = *(const bf16x8*)(src + c);
    }
}

// ---------------- PV fused: o = (QF @ ctx^T) * dinv; sums 8 ctx chunks in staging -----
// B rows 0..63 = ctx^T, row 64 = ksum, 65..79 = 0. Each wave owns 64 distinct rows.
__global__ __launch_bounds__(256, 2) void pv_fused(
    const bf16_t* __restrict__ QF,        // [12][4096][256]
    const float* __restrict__ CTXc,       // [12][8][80][256] split-K chunks
    bf16_t* __restrict__ O)               // [4096][768]
{
    __shared__ __align__(16) bf16_t As[256 * 64];   // 32 KB
    __shared__ __align__(16) bf16_t Bs[80 * 64];    // 10 KB
    const int h = blockIdx.y;
    const int tileM = blockIdx.x * 256;
    const int t = threadIdx.x, wave = t >> 6, lane = t & 63;
    const int q = lane >> 4, r = lane & 15;

    f32x4 acc[4][5] = {};
    for (int kt = 0; kt < 256; kt += 64) {
#pragma unroll
        for (int i = 0; i < 8; i++) {
            const int c = i * 256 + t;
            gl_lds16(QF + ((long)h * 4096 + tileM + (c >> 3)) * 256 + kt + (c & 7) * 8,
                     (char*)As + (i * 256 + wave * 64) * 16);
        }
#pragma unroll
        for (int u = 0; u < 5; u++) {
            const int idx = u * 256 + t;          // 1280 = 80*16
            const int row = idx >> 4, c4 = (idx & 15) * 4;
            float4 s = {0.f, 0.f, 0.f, 0.f};
#pragma unroll
            for (int ch = 0; ch < 8; ch++) {
                const float4 v = *(const float4*)(CTXc + ((long)(h * 8 + ch) * 80 + row) * 256 + kt + c4);
                s.x += v.x; s.y += v.y; s.z += v.z; s.w += v.w;
            }
            bf16x4 o4; o4[0] = (bf16_t)s.x; o4[1] = (bf16_t)s.y; o4[2] = (bf16_t)s.z; o4[3] = (bf16_t)s.w;
            *(bf16x4*)(Bs + row * 64 + c4) = o4;
        }
        __syncthreads();
#pragma unroll
        for (int kk = 0; kk < 64; kk += 32) {
            bf16x8 af[4], bfr[5];
#pragma unroll
            for (int i = 0; i < 4; i++)
                af[i] = *(const bf16x8*)(As + (wave * 64 + i * 16 + r) * 64 + kk + q * 8);
#pragma unroll
            for (int j = 0; j < 5; j++)
                bfr[j] = *(const bf16x8*)(Bs + (j * 16 + r) * 64 + kk + q * 8);
#pragma unroll
            for (int i = 0; i < 4; i++)
#pragma unroll
                for (int j = 0; j < 5; j++)
                    acc[i][j] = __builtin_amdgcn_mfma_f32_16x16x32_bf16(af[i], bfr[j], acc[i][j], 0, 0, 0);
        }
        __syncthreads();
    }
#pragma unroll
    for (int i = 0; i < 4; i++) {
#pragma unroll
        for (int e = 0; e < 4; e++) {
            const int R = tileM + wave * 64 + i * 16 + q * 4 + e;
            const float den = __shfl(acc[i][4][e], lane & 0x30);   // col 64 = ksum dot (r==0)
            const float dinv = 1.0f / den;
            bf16_t* op = O + (long)R * 768 + h * 64;
#pragma unroll
            for (int j = 0; j < 4; j++)
                op[j * 16 + r] = (bf16_t)(acc[i][j][e] * dinv);
        }
    }
}

// ---------------- bucketize + mask ----------------
__global__ void bucket_kernel(const float* __restrict__ methy, int* __restrict__ idx, float* __restrict__ maskf) {
    const int n = blockIdx.x * 256 + threadIdx.x;
    if (n >= NTOK) return;
    const float u = methy[n];
    int cnt = (int)(u > -2.0f) + (int)(u > -1.0f);
    for (int k = 0; k < 100; k++) cnt += (int)(((float)k * 0.01f) < u);
    idx[n] = cnt;
    maskf[n] = (u != 0.0f) ? 1.0f : 0.0f;
}

// ---------------- embedding gather ----------------
__global__ void embed_kernel(const int* __restrict__ idx, const int* __restrict__ pos, const int* __restrict__ chromo,
                             const float* __restrict__ mt, const float* __restrict__ pt, const float* __restrict__ ct,
                             float* __restrict__ X) {
    const int n = blockIdx.x, t = threadIdx.x;
    const float4* a = (const float4*)(mt + (long)idx[n] * DIM);
    const float4* b = (const float4*)(pt + (long)pos[n] * DIM);
    const float4* c = (const float4*)(ct + (long)chromo[n] * DIM);
    float4 rr = a[t];
    const float4 u = b[t], w = c[t];
    rr.x += u.x + w.x; rr.y += u.y + w.y; rr.z += u.z + w.z; rr.w += u.w + w.w;
    ((float4*)(X + (long)n * DIM))[t] = rr;
}

// ---------------- fused residual (bf16 partials) + layernorm -> bf16 ------------------
__global__ __launch_bounds__(256) void ln_fused(float* __restrict__ X,
        const bf16_t* __restrict__ D0, const bf16_t* __restrict__ D1, const float* __restrict__ rb,
        const float* __restrict__ g, const float* __restrict__ b, bf16_t* __restrict__ out) {
    const int n = blockIdx.x, t = threadIdx.x;
    float* x = X + (long)n * DIM;
    float v[3];
#pragma unroll
    for (int j = 0; j < 3; j++) {
        const int c = t + j * 256;
        float xv = x[c];
        if (D0) {
            xv += (float)D0[(long)n * DIM + c] + (float)D1[(long)n * DIM + c] + rb[c];
            x[c] = xv;
        }
        v[j] = xv;
    }
    float s = v[0] + v[1] + v[2];
    float s2 = v[0] * v[0] + v[1] * v[1] + v[2] * v[2];
    __shared__ float smA[4], smB[4];
    for (int o = 32; o; o >>= 1) { s += __shfl_down(s, o); s2 += __shfl_down(s2, o); }
    if ((t & 63) == 0) { smA[t >> 6] = s; smB[t >> 6] = s2; }
    __syncthreads();
    s = smA[0] + smA[1] + smA[2] + smA[3];
    s2 = smB[0] + smB[1] + smB[2] + smB[3];
    const float mu = s * (1.0f / DIM);
    const float var = s2 * (1.0f / DIM) - mu * mu;
    const float rs = rsqrtf(var + 1e-5f);
    bf16_t* op = out + (long)n * DIM;
#pragma unroll
    for (int j = 0; j < 3; j++) {
        const int c = t + j * 256;
        op[c] = (bf16_t)((v[j] - mu) * rs * g[c] + b[c]);
    }
}

// ---------------- batched transpose of the 4 square weights (Wq,Wk,Wv,Wo) ------------
__global__ __launch_bounds__(256) void transpose4(const float* __restrict__ Wq, const float* __restrict__ Wk,
        const float* __restrict__ Wv, const float* __restrict__ Wo,
        bf16_t* __restrict__ WqkvT, bf16_t* __restrict__ WoT) {
    __shared__ float tile[32][33];
    const int z = blockIdx.z, l = z >> 2, j = z & 3;
    const float* in = (j == 0 ? Wq : j == 1 ? Wk : j == 2 ? Wv : Wo) + (long)l * 768 * 768;
    bf16_t* out = (j < 3) ? WqkvT + (long)l * 2304 * 768 + (long)j * 768 * 768
                          : WoT + (long)l * 768 * 768;
    const int c0 = blockIdx.x * 32, r0 = blockIdx.y * 32;
    const int t = threadIdx.x, tx = t & 31, ty = t >> 5;
    for (int i = 0; i < 32; i += 8)
        tile[ty + i][tx] = in[(long)(r0 + ty + i) * 768 + c0 + tx];
    __syncthreads();
    for (int i = 0; i < 32; i += 8)
        out[(long)(c0 + ty + i) * 768 + r0 + tx] = (bf16_t)tile[tx][ty + i];
}

// ---------------- generic guarded transpose (W1, W2, Wout) ----------------
__global__ __launch_bounds__(256) void transpose_b(const float* __restrict__ in, long sIn, int R, int C,
                                                   bf16_t* __restrict__ out, long sOut, int ldo) {
    __shared__ float tile[32][33];
    in += (long)blockIdx.z * sIn;
    out += (long)blockIdx.z * sOut;
    const int c0 = blockIdx.x * 32, r0 = blockIdx.y * 32;
    const int t = threadIdx.x, tx = t & 31, ty = t >> 5;
    for (int i = 0; i < 32; i += 8) {
        const int rr = r0 + ty + i, cc = c0 + tx;
        tile[ty + i][tx] = (rr < R && cc < C) ? in[(long)rr * C + cc] : 0.0f;
    }
    __syncthreads();
    for (int i = 0; i < 32; i += 8) {
        const int cc = c0 + ty + i, rr = r0 + tx;
        if (cc < C && rr < R) out[(long)cc * ldo + rr] = (bf16_t)tile[tx][ty + i];
    }
}

__global__ void conv_kernel(const float* __restrict__ in, bf16_t* __restrict__ out, long n) {
    const long i = ((long)blockIdx.x * 256 + threadIdx.x) * 4;
    if (i >= n) return;
    const float4 v = *(const float4*)(in + i);
    bf16x4 o; o[0] = (bf16_t)v.x; o[1] = (bf16_t)v.y; o[2] = (bf16_t)v.z; o[3] = (bf16_t)v.w;
    *(bf16x4*)(out + i) = o;
}

__global__ void vtones_kernel(bf16_t* __restrict__ VT) {   // VT[h][64][n] = 1
    const int i = blockIdx.x * 256 + threadIdx.x;          // 12*4096
    const int h = i >> 12, n = i & 4095;
    VT[((long)h * 128 + 64) * 4096 + n] = (bf16_t)1.0f;
}

extern "C" void kernel_launch(void* const* d_in, const int* in_sizes, int n_in,
                              void* d_out, int out_size, void* d_ws, size_t ws_size,
                              hipStream_t stream) {
    const float* methy        = (const float*)d_in[0];
    const int*   chromo       = (const int*)d_in[1];
    const int*   pos          = (const int*)d_in[2];
    const float* methy_table  = (const float*)d_in[3];
    const float* chromo_table = (const float*)d_in[4];
    const float* pos_table    = (const float*)d_in[5];
    const float* ln1_g = (const float*)d_in[6];
    const float* ln1_b = (const float*)d_in[7];
    const float* ln2_g = (const float*)d_in[8];
    const float* ln2_b = (const float*)d_in[9];
    const float* Wq = (const float*)d_in[10];
    const float* Wk = (const float*)d_in[11];
    const float* Wv = (const float*)d_in[12];
    const float* Wo = (const float*)d_in[13];
    const float* bo = (const float*)d_in[14];
    const float* W1 = (const float*)d_in[15];
    const float* b1 = (const float*)d_in[16];
    const float* W2 = (const float*)d_in[17];
    const float* b2 = (const float*)d_in[18];
    const float* proj = (const float*)d_in[19];
    const float* normf_g = (const float*)d_in[20];
    const float* normf_b = (const float*)d_in[21];
    const float* Wout = (const float*)d_in[22];
    const float* bout = (const float*)d_in[23];

    char* p = (char*)d_ws;
    auto alloc = [&](size_t bytes) { char* r = p; p += (bytes + 255) & ~(size_t)255; return r; };

    float*  X     = (float*)alloc((size_t)NTOK * DIM * 4);
    bf16_t* Hbf   = (bf16_t*)alloc((size_t)NTOK * DIM * 2);
    bf16_t* G     = (bf16_t*)alloc((size_t)NTOK * FFD * 2);
    bf16_t* D     = (bf16_t*)alloc((size_t)2 * NTOK * DIM * 2);  // bf16 split-K partials
    bf16_t* QKbf  = (bf16_t*)alloc((size_t)NTOK * 1536 * 2);     // reused as O
    bf16_t* O     = QKbf;
    bf16_t* VT    = (bf16_t*)alloc((size_t)12 * 128 * 4096 * 2); // kmx MUST follow
    unsigned* kmx = (unsigned*)alloc(64);                        // right after VT (MODE 8 uses aux+off)
    bf16_t* QF    = (bf16_t*)alloc((size_t)12 * 4096 * 256 * 2);
    bf16_t* KFT   = (bf16_t*)alloc((size_t)12 * 256 * 4096 * 2);
    bf16_t* WqkvT = (bf16_t*)alloc((size_t)DEPTH * 2304 * 768 * 2);
    bf16_t* WoT   = (bf16_t*)alloc((size_t)DEPTH * 768 * 768 * 2);
    bf16_t* W1T   = (bf16_t*)alloc((size_t)DEPTH * 3072 * 768 * 2);
    bf16_t* W2T   = (bf16_t*)alloc((size_t)DEPTH * 768 * 3072 * 2);
    bf16_t* projbf= (bf16_t*)alloc((size_t)DEPTH * 256 * 64 * 2);
    bf16_t* WoutT = (bf16_t*)alloc((size_t)128 * 768 * 2);
    float*  diagQ = (float*)alloc((size_t)12 * 4096 * 4);
    float*  diagK = (float*)alloc((size_t)12 * 4096 * 4);
    float*  CTXc  = (float*)alloc((size_t)12 * 8 * 80 * 256 * 4);  // split-K ctx chunks
    int*    idxb  = (int*)alloc((size_t)4096 * 4);
    float*  maskf = (float*)alloc((size_t)4096 * 4);

    hipMemsetAsync(VT, 0, (size_t)12 * 128 * 4096 * 2, stream);  // rows 65..127 stay 0
    hipMemsetAsync(WoutT, 0, (size_t)128 * 768 * 2, stream);
    hipMemsetAsync(d_out, 0, (size_t)out_size * 4, stream);      // logits accumulate via atomics
    vtones_kernel<<<192, 256, 0, stream>>>(VT);                   // row 64 = ones (persists)

    bucket_kernel<<<16, 256, 0, stream>>>(methy, idxb, maskf);
    embed_kernel<<<4096, 192, 0, stream>>>(idxb, pos, chromo, methy_table, pos_table, chromo_table, X);

    const long s768 = (long)768 * 768, sQKV = (long)2304 * 768, sFF = (long)3072 * 768;
    transpose4<<<dim3(24, 24, 4 * DEPTH), 256, 0, stream>>>(Wq, Wk, Wv, Wo, WqkvT, WoT);
    transpose_b<<<dim3(96, 24, DEPTH), 256, 0, stream>>>(W1, sFF, 768, 3072, W1T, sFF, 768);
    transpose_b<<<dim3(24, 96, DEPTH), 256, 0, stream>>>(W2, sFF, 3072, 768, W2T, sFF, 3072);
    transpose_b<<<dim3(4, 24, 1), 256, 0, stream>>>(Wout, 0, 768, VOUT, WoutT, 0, 768);
    conv_kernel<<<96, 256, 0, stream>>>(proj, projbf, (long)DEPTH * 256 * 64);

    bf16_t* D0 = D;
    bf16_t* D1 = D + (long)NTOK * DIM;

    for (int l = 0; l < DEPTH; l++) {
        const bf16_t* lWqkv = WqkvT + (long)l * sQKV;
        const bf16_t* lWo   = WoT + (long)l * s768;
        const bf16_t* lW1   = W1T + (long)l * sFF;
        const bf16_t* lW2   = W2T + (long)l * sFF;
        const bf16_t* lproj = projbf + (long)l * 256 * 64;

        // residual(prev FF2) + LN1
        if (l == 0)
            ln_fused<<<4096, 256, 0, stream>>>(X, nullptr, nullptr, nullptr, ln1_g, ln1_b, Hbf);
        else
            ln_fused<<<4096, 256, 0, stream>>>(X, D0, D1, b2 + (l - 1) * DIM,
                                               ln1_g + l * DIM, ln1_b + l * DIM, Hbf);

        gemm128<8><<<dim3(32, 18, 1), 256, 0, stream>>>(Hbf, 768, 0, lWqkv, 768, 0, QKbf, 1536, 0,
                                                        768, 1, diagQ, diagK, 4096, 2304, VT);
        qk_feat<<<dim3(32, 24), 256, 0, stream>>>(QKbf, lproj, diagQ, QF, kmx);
        kfeat_fused<<<dim3(32, 12), 256, 0, stream>>>(QKbf, lproj, diagK, kmx, maskf, KFT);

        // ctx (+ksum via ones row), split-K=8, plain stores to per-chunk buffers
        gemm128<9><<<dim3(1, 2, 96), 256, 0, stream>>>(VT, 4096, (long)128 * 4096, KFT, 4096, (long)256 * 4096,
                                                       CTXc, 256, (long)80 * 256, 4096, 8,
                                                       nullptr, nullptr, 80, 256, nullptr);
        pv_fused<<<dim3(16, 12), 256, 0, stream>>>(QF, CTXc, O);

        // Wo (split-K bf16 partials into D0/D1)
        gemm128<10><<<dim3(32, 6, 2), 256, 0, stream>>>(O, 768, 0, lWo, 768, 0, D, 768, (long)NTOK * DIM,
                                                        768, 2, nullptr, nullptr, 4096, 768, nullptr);
        ln_fused<<<4096, 256, 0, stream>>>(X, D0, D1, bo + l * DIM,
                                           ln2_g + l * DIM, ln2_b + l * DIM, Hbf);
        gemm128<2><<<dim3(32, 24, 1), 256, 0, stream>>>(Hbf, 768, 0, lW1, 768, 0, G, 3072, 0,
                                                        768, 1, b1 + l * FFD, nullptr, 4096, 3072, nullptr);
        gemm128<10><<<dim3(32, 6, 2), 256, 0, stream>>>(G, 3072, 0, lW2, 3072, 0, D, 768, (long)NTOK * DIM,
                                                        3072, 2, nullptr, nullptr, 4096, 768, nullptr);
    }

    // final residual + LN + logits (split-K=4, atomic accumulate onto zeroed d_out)
    ln_fused<<<4096, 256, 0, stream>>>(X, D0, D1, b2 + (DEPTH - 1) * DIM, normf_g, normf_b, Hbf);
    gemm128<4><<<dim3(32, 1, 4), 256, 0, stream>>>(Hbf, 768, 0, WoutT, 768, 0, d_out, VOUT, 0,
                                                   768, 4, bout, nullptr, 4096, VOUT, nullptr);
}